// Round 5
// baseline (309.719 us; speedup 1.0000x reference)
//
#include <hip/hip_runtime.h>
#include <hip/hip_bf16.h>
#include <math.h>

// Problem constants (reference: B=8, H=W=512)
#define Bsz    8
#define Wdim   512
#define HWv    (512 * 512)       // 262144 = 2^18
#define LOG2HW 18
#define NIMG   16                // {bg(0..7), fg(8..15)}
#define TILE   64                // 64x64 tiles -> 8x8 = 64 tiles per image
#define TPIX   (TILE * TILE)     // 4096

// ws layout (int32 units):
//   [0, NIMG*HWv)            labels (local pixel index within image, or -1)
//   [NIMG*HWv, 2*NIMG*HWv)   areas  (tile roots hold partial/total areas)
//   [2*NIMG*HWv, +16)        per-image max area
//   then (8-byte aligned):   double sums[2]; int counts[2]

// ---------------- union-find (atomicMin only: parents monotone decreasing,
// links point to smaller index => lock-free correct). ----------------
__device__ __forceinline__ int uf_find(int* L, int x) {
  int p = L[x];
  while (p != x) {
    int gp = L[p];
    if (gp != p) atomicMin(&L[x], gp);  // grandparent compression (monotone)
    x = gp;
    p = L[x];
  }
  return x;
}

// Read-only find: no compression writes.
__device__ __forceinline__ int find_ro(const int* __restrict__ L, int x) {
  int p = L[x];
  while (p != x) { x = p; p = L[x]; }
  return x;
}

__device__ __forceinline__ void uf_union(int* L, int a, int b) {
  a = uf_find(L, a);
  b = uf_find(L, b);
  while (a != b) {
    if (a < b) { int t = a; a = b; b = t; }  // ensure a > b
    int old = atomicMin(&L[a], b);
    if (old == a) return;  // linked a -> b
    a = old;               // parent already lowered; keep merging
  }
}

// ---------------- kernels ----------------

// Per-tile CCL in LDS, run-based: a wave == one 64-px row. Pixels link
// directly to their run start (ballot, no atomics); vertical unions only at
// the leftmost pixel of each overlap segment.
__global__ void k_local(const float* __restrict__ cams, int* __restrict__ labels,
                        int* __restrict__ areas) {
  int img  = blockIdx.x >> 6;          // 0..15
  int tile = blockIdx.x & 63;          // 8x8 tiles
  int tY = tile >> 3, tX = tile & 7;
  int b = img & 7;
  bool fg = (img & 8) != 0;
  int gbase = img << LOG2HW;
  int oy = tY * TILE, ox = tX * TILE;
  int lane = threadIdx.x & 63;

  __shared__ int P[TPIX];              // parents, 16 KB
  __shared__ int A[TPIX];              // local areas, 16 KB

  // pass 1: mask load + per-row run-start init (wave covers exactly one row)
  #pragma unroll
  for (int it = 0; it < 16; ++it) {
    int i  = it * 256 + threadIdx.x;   // i & 63 == lane
    int ly = i >> 6;
    float c = cams[(b << LOG2HW) + ((oy + ly) << 9) + (ox + lane)];
    bool m = fg ? (c > 0.6f) : (c >= 0.2f);
    unsigned long long bm = __ballot(m);
    int par = -1;
    if (m) {
      unsigned long long below = (1ULL << lane) - 1ULL;
      unsigned long long z = (~bm) & below;       // zeros below this lane
      int rs = z ? (64 - __clzll(z)) : 0;          // run start = highest zero + 1
      par = (ly << 6) + rs;
    }
    P[i] = par;
    A[i] = 0;
  }
  __syncthreads();

  // pass 2: vertical unions, one per overlap segment (dedup via west pair)
  #pragma unroll
  for (int it = 0; it < 16; ++it) {
    int i = it * 256 + threadIdx.x;
    if (i >= TILE && P[i] >= 0 && P[i - TILE] >= 0) {
      bool skip = (lane > 0) && (P[i - 1] >= 0) && (P[i - TILE - 1] >= 0);
      if (!skip) uf_union(P, i, i - TILE);
    }
  }
  __syncthreads();

  // pass 3: compress to root (plain store = maximal compression; stored
  // values are valid ancestors for concurrent readers) + aggregated areas
  #pragma unroll
  for (int it = 0; it < 16; ++it) {
    int i = it * 256 + threadIdx.x;
    int r = -1;
    if (P[i] >= 0) { r = find_ro(P, i); P[i] = r; }
    bool valid = r >= 0;
    unsigned long long pending = __ballot(valid);
    while (pending) {
      int leader = __ffsll((unsigned long long)pending) - 1;
      int lr = __shfl(r, leader);
      bool match = valid && (r == lr);
      unsigned long long mm = __ballot(match);
      if (lane == leader) atomicAdd(&A[lr], (int)__popcll(mm));
      pending &= ~mm;
      if (match) valid = false;
    }
  }
  __syncthreads();

  // pass 4: write labels (global idx of tile root) + root partial areas
  #pragma unroll
  for (int it = 0; it < 16; ++it) {
    int i  = it * 256 + threadIdx.x;
    int ly = i >> 6;
    int g  = ((oy + ly) << 9) + (ox + lane);
    int p  = P[i];
    int lab = -1;
    if (p >= 0) lab = ((oy + (p >> 6)) << 9) + (ox + (p & 63));
    labels[gbase + g] = lab;
    areas[gbase + g]  = (p == i) ? A[i] : 0;
  }
}

// Merge across tile boundaries, one union per contiguous overlap segment.
// Also folds the tiny init (maxa/sums/counts) into block 0.
__global__ void k_border(int* __restrict__ labels, int* __restrict__ maxa,
                         double* __restrict__ sums, int* __restrict__ counts) {
  if (blockIdx.x == 0) {
    if (threadIdx.x < NIMG) maxa[threadIdx.x] = 0;
    if (threadIdx.x < 2) { sums[threadIdx.x] = 0.0; counts[threadIdx.x] = 0; }
  }
  const int per_img = 14 * Wdim;       // 7168
  int t = blockIdx.x * blockDim.x + threadIdx.x;
  if (t >= NIMG * per_img) return;
  int img = t / per_img;
  int r   = t - img * per_img;
  int k = r >> 9, j = r & (Wdim - 1);
  int* L = labels + (img << LOG2HW);
  // mask-ness (>=0 vs -1) of label slots is immutable during this kernel, so
  // the dedup checks are stable under concurrent unions.
  if (k < 7) {                          // vertical border: x = 64k+63, union east
    int x = TILE * k + (TILE - 1);
    int p = (j << 9) + x, q = p + 1;    // j = y
    if (L[p] >= 0 && L[q] >= 0) {
      bool skip = (j > 0) && (L[p - Wdim] >= 0) && (L[q - Wdim] >= 0);
      if (!skip) uf_union(L, p, q);
    }
  } else {                              // horizontal border: y = 64(k-7)+63, union south
    int y = TILE * (k - 7) + (TILE - 1);
    int p = (y << 9) + j, q = p + Wdim; // j = x
    if (L[p] >= 0 && L[q] >= 0) {
      bool skip = (j > 0) && (L[p - 1] >= 0) && (L[q - 1] >= 0);
      if (!skip) uf_union(L, p, q);
    }
  }
}

// Resolve 4 px/thread to final roots (independent finds = ILP); push tile-root
// partial areas into final roots. Adds only target final roots; a final
// root's own slot is never zeroed.
__global__ void k_flatten(int* __restrict__ labels, int* __restrict__ areas) {
  int t = blockIdx.x * blockDim.x + threadIdx.x;
  int idx0 = t << 2;
  int img  = idx0 >> LOG2HW;           // 4 px never straddle an image
  int base = img << LOG2HW;
  int* L = labels + base;
  int4 lab = *(const int4*)&labels[idx0];
  int4 ar  = *(const int4*)&areas[idx0];
  int self0 = idx0 - base;
  int r0 = lab.x >= 0 ? find_ro(L, lab.x) : -1;
  int r1 = lab.y >= 0 ? find_ro(L, lab.y) : -1;
  int r2 = lab.z >= 0 ? find_ro(L, lab.z) : -1;
  int r3 = lab.w >= 0 ? find_ro(L, lab.w) : -1;
  int4 out; out.x = r0; out.y = r1; out.z = r2; out.w = r3;
  *(int4*)&labels[idx0] = out;         // -1 stays -1
  if (ar.x > 0 && r0 != self0)     { atomicAdd(&areas[base + r0], ar.x); areas[idx0]     = 0; }
  if (ar.y > 0 && r1 != self0 + 1) { atomicAdd(&areas[base + r1], ar.y); areas[idx0 + 1] = 0; }
  if (ar.z > 0 && r2 != self0 + 2) { atomicAdd(&areas[base + r2], ar.z); areas[idx0 + 2] = 0; }
  if (ar.w > 0 && r3 != self0 + 3) { atomicAdd(&areas[base + r3], ar.w); areas[idx0 + 3] = 0; }
}

// Per-image max area: int4 streaming read, block-level max, 1 atomic/block.
__global__ void k_max(const int* __restrict__ areas, int* __restrict__ maxa) {
  int vidx = blockIdx.x * blockDim.x + threadIdx.x;   // int4 index
  const int4* a4 = (const int4*)areas;
  int4 v = a4[vidx];
  int m = max(max(v.x, v.y), max(v.z, v.w));
  #pragma unroll
  for (int off = 32; off > 0; off >>= 1)
    m = max(m, __shfl_down(m, off));
  __shared__ int lm[4];
  int wave = threadIdx.x >> 6;
  if ((threadIdx.x & 63) == 0) lm[wave] = m;
  __syncthreads();
  if (threadIdx.x == 0) {
    int bm = max(max(lm[0], lm[1]), max(lm[2], lm[3]));
    if (bm > 0) {
      int img = (vidx * 4) >> LOG2HW;
      atomicMax(&maxa[img], bm);
    }
  }
}

// 4 px/thread, float4 preds loads, softplus form (1 exp + 1 log shared
// between fg and bg terms): lse-l1 = max(d,0)+log(1+e^-|d|), d = l0-l1.
__global__ void k_ce(const float* __restrict__ preds, const int* __restrict__ labels,
                     const int* __restrict__ areas, const int* __restrict__ maxa,
                     double* __restrict__ sums, int* __restrict__ counts) {
  int t = blockIdx.x * blockDim.x + threadIdx.x;      // 0..524287
  int idx0 = t << 2;
  int b  = idx0 >> LOG2HW;
  int p0 = idx0 & (HWv - 1);
  int4 lb = *(const int4*)&labels[idx0];
  int4 lf = *(const int4*)&labels[(8 << LOG2HW) + idx0];
  int maxb = maxa[b], maxf = maxa[8 + b];
  const int* ab = areas + (b << LOG2HW);
  const int* af = areas + ((8 + b) << LOG2HW);
  bool vf[4], vb[4];
  {
    int l[4] = {lb.x, lb.y, lb.z, lb.w};
    int m[4] = {lf.x, lf.y, lf.z, lf.w};
    #pragma unroll
    for (int j = 0; j < 4; j++) {
      bool kb = (l[j] >= 0) && (2 * ab[l[j]] > maxb);
      bool kf = (m[j] >= 0) && (2 * af[m[j]] > maxf);
      vb[j] = !kb;                     // bg valid where NOT kept
      vf[j] = kf;                      // fg valid where kept
    }
  }
  int cf = (int)vf[0] + vf[1] + vf[2] + vf[3];
  int cb = (int)vb[0] + vb[1] + vb[2] + vb[3];
  float sfg = 0.f, sbg = 0.f;
  if (cf + cb > 0) {
    #pragma unroll
    for (int i = 0; i < 3; i++) {
      const float* pb = preds + ((size_t)((i * Bsz + b) * 2) << LOG2HW);
      float4 L0 = *(const float4*)&pb[p0];
      float4 L1 = *(const float4*)&pb[HWv + p0];
      float d[4] = {L0.x - L1.x, L0.y - L1.y, L0.z - L1.z, L0.w - L1.w};
      #pragma unroll
      for (int j = 0; j < 4; j++) {
        float sp = logf(1.f + expf(-fabsf(d[j])));
        if (vf[j]) sfg += fmaxf(d[j], 0.f) + sp;
        if (vb[j]) sbg += fmaxf(-d[j], 0.f) + sp;
      }
    }
  }
  // block reduction: wave64 shuffle -> LDS -> 4 atomics/block
  #pragma unroll
  for (int off = 32; off > 0; off >>= 1) {
    sfg += __shfl_down(sfg, off);
    sbg += __shfl_down(sbg, off);
    cf  += __shfl_down(cf, off);
    cb  += __shfl_down(cb, off);
  }
  __shared__ float lsf[4], lsb[4];
  __shared__ int   lcf[4], lcb[4];
  int wave = threadIdx.x >> 6;
  if ((threadIdx.x & 63) == 0) {
    lsf[wave] = sfg; lsb[wave] = sbg; lcf[wave] = cf; lcb[wave] = cb;
  }
  __syncthreads();
  if (threadIdx.x == 0) {
    float tf = 0.f, tb = 0.f; int af_ = 0, ab_ = 0;
    #pragma unroll
    for (int w = 0; w < 4; w++) { tf += lsf[w]; tb += lsb[w]; af_ += lcf[w]; ab_ += lcb[w]; }
    atomicAdd(&sums[0], (double)tf);
    atomicAdd(&sums[1], (double)tb);
    atomicAdd(&counts[0], af_);
    atomicAdd(&counts[1], ab_);
  }
}

__global__ void k_final(const double* __restrict__ sums, const int* __restrict__ counts,
                        float* __restrict__ out) {
  if (threadIdx.x == 0 && blockIdx.x == 0) {
    double df = counts[0] > 0 ? (double)counts[0] : 1.0;
    double db = counts[1] > 0 ? (double)counts[1] : 1.0;
    out[0] = (float)(sums[0] / df + sums[1] / db);
  }
}

extern "C" void kernel_launch(void* const* d_in, const int* in_sizes, int n_in,
                              void* d_out, int out_size, void* d_ws, size_t ws_size,
                              hipStream_t stream) {
  (void)in_sizes; (void)n_in; (void)out_size; (void)ws_size;
  const float* preds = (const float*)d_in[0];  // [3,8,2,512,512] f32
  const float* cams  = (const float*)d_in[1];  // [8,1,512,512]  f32
  float* out = (float*)d_out;                  // scalar f32

  int* labels = (int*)d_ws;
  int* areas  = labels + NIMG * HWv;
  int* maxa   = areas + NIMG * HWv;
  double* sums = (double*)(maxa + 16);
  int* counts  = (int*)(sums + 2);

  const int threads = 256;

  k_local  <<<NIMG * 64, threads, 0, stream>>>(cams, labels, areas);
  k_border <<<(NIMG * 14 * Wdim + threads - 1) / threads, threads, 0, stream>>>(labels, maxa, sums, counts);
  k_flatten<<<NIMG * HWv / (threads * 4), threads, 0, stream>>>(labels, areas);
  k_max    <<<NIMG * HWv / (threads * 4), threads, 0, stream>>>(areas, maxa);
  k_ce     <<<Bsz * HWv / (threads * 4), threads, 0, stream>>>(preds, labels, areas, maxa, sums, counts);
  k_final  <<<1, 64, 0, stream>>>(sums, counts, out);
}